// Round 7
// baseline (899.308 us; speedup 1.0000x reference)
//
#include <hip/hip_runtime.h>
#include <hip/hip_bf16.h>
#include <stdint.h>

#define B_   32768
#define JN   57
#define QSTR 256      // q row stride (228 padded to 256)

typedef _Float16 f16x8 __attribute__((ext_vector_type(8)));
typedef float    f32x4 __attribute__((ext_vector_type(4)));

__device__ __forceinline__ void split_f16(float v, _Float16& hi, _Float16& lo) {
  hi = (_Float16)v;
  lo = (_Float16)(v - (float)hi);
}

// ---------------- prep kernels ----------------
__global__ void prep_x2_kernel(const float* __restrict__ x, _Float16* __restrict__ xp) {
  long i = (long)blockIdx.x * 256 + threadIdx.x;   // over B_*192
  int row = (int)(i / 192), col = (int)(i % 192);
  float v = (col < 171) ? x[(long)row * 171 + col] : 0.f;
  _Float16 hi, lo; split_f16(v, hi, lo);
  xp[(long)row * 384 + col]       = hi;
  xp[(long)row * 384 + 192 + col] = lo;
}

__global__ void prep_w2_kernel(const float* __restrict__ w, _Float16* __restrict__ wf,
                               int Ksrc, int Kpad, int Nsrc) {
  long i = (long)blockIdx.x * 256 + threadIdx.x;   // over Ndst*Kpad
  int n = (int)(i / Kpad), k = (int)(i % Kpad);
  float v = (k < Ksrc && n < Nsrc) ? w[(long)k * Nsrc + n] : 0.f;
  _Float16 hi, lo; split_f16(v, hi, lo);
  wf[(long)n * (2 * Kpad) + k]        = hi;
  wf[(long)n * (2 * Kpad) + Kpad + k] = lo;
}

__global__ void prep_b4_kernel(const float* __restrict__ b, float* __restrict__ bp) {
  int i = threadIdx.x;  // 256 threads
  bp[i] = (i < 228) ? b[i] : 0.f;
}

// ---------------- 128² split-f16 GEMM (m97 structure) — used for layer 1 only ----------------
template<int EPI>
__global__ __launch_bounds__(256)
void gemm_hl(const _Float16* __restrict__ A, const _Float16* __restrict__ Bt,
             const float* __restrict__ bias, void* __restrict__ Cout,
             int M, int N, int Kp)
{
  __shared__ __align__(16) _Float16 As[128 * 64];
  __shared__ __align__(16) _Float16 Bs[128 * 64];
  const int lda = 2 * Kp;
  const int T = Kp >> 6;
  const int tiles_n = N >> 7;
  const int cpx  = gridDim.x >> 3;
  const int virt = (blockIdx.x & 7) * cpx + (blockIdx.x >> 3);
  const int bm = virt / tiles_n;
  const int bn = virt % tiles_n;
  const int tid  = threadIdx.x;
  const int wave = tid >> 6;
  const int lane = tid & 63;

  const int srow = wave * 8 + (lane >> 3);
  const int scol = (((lane & 7) ^ (lane >> 3)) * 8);
  const long abase = (long)bm * 128;
  const long bbase = (long)bn * 128;

  f32x4 acc[4][4] = {};

  const int wm = (wave >> 1) * 64;
  const int wn = (wave & 1) * 64;
  const int lr = lane & 15;
  const int ch0 = (((lane >> 4) ^ (lane & 7)) * 8);
  const int ch1 = (((4 + (lane >> 4)) ^ (lane & 7)) * 8);

  for (int ph = 0; ph < 3; ++ph) {
    const int aoff = (ph == 2) ? Kp : 0;
    const int boff = (ph == 1) ? Kp : 0;
    for (int u = 0; u < T; ++u) {
#pragma unroll
      for (int i = 0; i < 4; i++) {
        const _Float16* asrc = A  + (abase + i * 32 + srow) * (long)lda + (aoff + u * 64 + scol);
        const _Float16* bsrc = Bt + (bbase + i * 32 + srow) * (long)lda + (boff + u * 64 + scol);
        __builtin_amdgcn_global_load_lds(
            (const __attribute__((address_space(1))) void*)asrc,
            (__attribute__((address_space(3))) void*)(As + (i * 256 + wave * 64) * 8),
            16, 0, 0);
        __builtin_amdgcn_global_load_lds(
            (const __attribute__((address_space(1))) void*)bsrc,
            (__attribute__((address_space(3))) void*)(Bs + (i * 256 + wave * 64) * 8),
            16, 0, 0);
      }
      __syncthreads();

#pragma unroll
      for (int ks = 0; ks < 2; ks++) {
        const int ch = ks ? ch1 : ch0;
        f16x8 af[4], bfr[4];
#pragma unroll
        for (int m = 0; m < 4; m++)
          af[m] = *(const f16x8*)(As + (wm + m * 16 + lr) * 64 + ch);
#pragma unroll
        for (int n = 0; n < 4; n++)
          bfr[n] = *(const f16x8*)(Bs + (wn + n * 16 + lr) * 64 + ch);
#pragma unroll
        for (int m = 0; m < 4; m++)
#pragma unroll
          for (int n = 0; n < 4; n++)
            acc[m][n] = __builtin_amdgcn_mfma_f32_16x16x32_f16(af[m], bfr[n], acc[m][n], 0, 0, 0);
      }
      __syncthreads();
    }
  }

  const int crow0 = bm * 128 + wm + (lane >> 4) * 4;
  const int ccol0 = bn * 128 + wn + lr;
#pragma unroll
  for (int n = 0; n < 4; n++) {
    const int col = ccol0 + n * 16;
    const float bv = bias[col];
#pragma unroll
    for (int m = 0; m < 4; m++) {
#pragma unroll
      for (int r = 0; r < 4; r++) {
        float v = acc[m][n][r] + bv;
        const long row = crow0 + m * 16 + r;
        if (EPI == 0) {
          v = (v >= 0.f) ? v : 0.01f * v;
          _Float16 hi, lo; split_f16(v, hi, lo);
          _Float16* C = (_Float16*)Cout;
          C[row * (long)(2 * N) + col]     = hi;
          C[row * (long)(2 * N) + N + col] = lo;
        } else {
          ((float*)Cout)[row * (long)N + col] = v;
        }
      }
    }
  }
}

// ---------------- 256² 8-phase split-f16 GEMM (T1+T2+T3+T4+T5) ----------------
// 512 thr = 8 waves (2M x 4N), per-wave 128x64 out. BK=64, 2 LDS slots (128KB).
// Virtual K-tile t: ph=t/T selects {AhBh, AhBl, AlBh}; NT = 3T (even for T even).
// Iter i: P1-P4 compute tile 2i from S0, staging tile 2i+1 halves into S1
// (Ah0,Ah1,Bh0,Bh1 — one half = 2 global_load_lds/thread per phase);
// P5-P8 symmetric (compute 2i+1 from S1, stage 2i+2 into S0).
// Raw s_barrier (no vmcnt drain); vmcnt(2) only at P1/P5 (waits exactly the
// 8 loads of the tile about to be read; the 2 just-issued may fly).
template<int EPI>
__global__ __launch_bounds__(512, 2)
void gemm256(const _Float16* __restrict__ Ag, const _Float16* __restrict__ Bt,
             const float* __restrict__ bias, void* __restrict__ Cout,
             int M, int N, int Kp)
{
  __shared__ __align__(16) _Float16 As[2][256 * 64];
  __shared__ __align__(16) _Float16 Bs[2][256 * 64];
  const int lda = 2 * Kp;
  const int T  = Kp >> 6;
  const int NT = 3 * T;
  const int NI = NT >> 1;
  const int tiles_n = N >> 8;
  const int cpx  = gridDim.x >> 3;
  const int virt = (blockIdx.x & 7) * cpx + (blockIdx.x >> 3);
  const int bm = virt / tiles_n;
  const int bn = virt % tiles_n;
  const int tid  = threadIdx.x;
  const int wid  = tid >> 6;
  const int lane = tid & 63;

  const long abase = (long)bm * 256;
  const long bbase = (long)bn * 256;
  // staging: row(within half) = (tid>>3) + L*64; chunk pre-swizzled by row&7
  const int scol = (((lane & 7) ^ ((tid >> 3) & 7)) * 8);

  const int wm = (wid >> 2) * 128;
  const int wn = (wid & 3) * 64;
  const int lr = lane & 15;

  f32x4 acc[8][4] = {};

  // ---- staging helpers: one half (=2 loads) of tile t into slot s ----
  auto stageA = [&](int t, int s, int h) {
    const int ph = t / T, u = t - ph * T;
    const long ko = ((ph == 2) ? (long)Kp : 0) + u * 64 + scol;
    const _Float16* src = Ag + (abase + h * 128 + (tid >> 3)) * (long)lda + ko;
    const _Float16* dst = &As[s][h * 8192 + tid * 8];
    __builtin_amdgcn_global_load_lds(
        (const __attribute__((address_space(1))) void*)src,
        (__attribute__((address_space(3))) void*)dst, 16, 0, 0);
    __builtin_amdgcn_global_load_lds(
        (const __attribute__((address_space(1))) void*)(src + 64 * (long)lda),
        (__attribute__((address_space(3))) void*)(dst + 4096), 16, 0, 0);
  };
  auto stageB = [&](int t, int s, int h) {
    const int ph = t / T, u = t - ph * T;
    const long ko = ((ph == 1) ? (long)Kp : 0) + u * 64 + scol;
    const _Float16* src = Bt + (bbase + h * 128 + (tid >> 3)) * (long)lda + ko;
    const _Float16* dst = &Bs[s][h * 8192 + tid * 8];
    __builtin_amdgcn_global_load_lds(
        (const __attribute__((address_space(1))) void*)src,
        (__attribute__((address_space(3))) void*)dst, 16, 0, 0);
    __builtin_amdgcn_global_load_lds(
        (const __attribute__((address_space(1))) void*)(src + 64 * (long)lda),
        (__attribute__((address_space(3))) void*)(dst + 4096), 16, 0, 0);
  };

#define FRAG_READS(slot, mh, ks)                                                  \
    const int ch = (((ks) * 4 + (lane >> 4)) ^ (lane & 7)) * 8;                   \
    f16x8 af[4], bfr[4];                                                          \
    _Pragma("unroll")                                                             \
    for (int mi = 0; mi < 4; ++mi)                                                \
      af[mi] = *(const f16x8*)&As[slot][(wm + (mh) * 64 + mi * 16 + lr) * 64 + ch]; \
    _Pragma("unroll")                                                             \
    for (int n = 0; n < 4; ++n)                                                   \
      bfr[n] = *(const f16x8*)&Bs[slot][(wn + n * 16 + lr) * 64 + ch];

#define MFMA16(mh)                                                                \
    __builtin_amdgcn_s_setprio(1);                                                \
    _Pragma("unroll")                                                             \
    for (int mi = 0; mi < 4; ++mi)                                                \
      _Pragma("unroll")                                                           \
      for (int n = 0; n < 4; ++n)                                                 \
        acc[(mh) * 4 + mi][n] = __builtin_amdgcn_mfma_f32_16x16x32_f16(           \
            af[mi], bfr[n], acc[(mh) * 4 + mi][n], 0, 0, 0);                      \
    __builtin_amdgcn_s_setprio(0);

  // wait-phase: stage first, wait the previous tile's 8 loads, barrier, read
#define PH_WAIT(slot, mh, ks, STAGE)                                              \
  do {                                                                            \
    STAGE;                                                                        \
    asm volatile("s_waitcnt vmcnt(2)" ::: "memory");                              \
    __builtin_amdgcn_s_barrier();                                                 \
    FRAG_READS(slot, mh, ks)                                                      \
    MFMA16(mh)                                                                    \
    __builtin_amdgcn_s_barrier();                                                 \
  } while (0)

  // mid-phase: reads first (data guaranteed since the tile's wait-phase barrier)
#define PH_MID(slot, mh, ks, STAGE)                                               \
  do {                                                                            \
    FRAG_READS(slot, mh, ks)                                                      \
    STAGE;                                                                        \
    __builtin_amdgcn_s_barrier();                                                 \
    MFMA16(mh)                                                                    \
    __builtin_amdgcn_s_barrier();                                                 \
  } while (0)

  // prologue: full tile 0 -> S0 (8 loads/thread)
  stageA(0, 0, 0); stageA(0, 0, 1); stageB(0, 0, 0); stageB(0, 0, 1);

  for (int i = 0; i < NI; ++i) {
    const int b = 2 * i + 1;
    const int c = (2 * i + 2 < NT) ? 2 * i + 2 : 0;   // tail: harmless re-stage
    PH_WAIT(0, 0, 0, stageA(b, 1, 0));
    PH_MID (0, 1, 0, stageA(b, 1, 1));
    PH_MID (0, 0, 1, stageB(b, 1, 0));
    PH_MID (0, 1, 1, stageB(b, 1, 1));
    PH_WAIT(1, 0, 0, stageA(c, 0, 0));
    PH_MID (1, 1, 0, stageA(c, 0, 1));
    PH_MID (1, 0, 1, stageB(c, 0, 0));
    PH_MID (1, 1, 1, stageB(c, 0, 1));
  }
  asm volatile("s_waitcnt vmcnt(0)" ::: "memory");

#undef PH_WAIT
#undef PH_MID
#undef FRAG_READS
#undef MFMA16

  // epilogue: C/D layout col=lane&15, row=(lane>>4)*4+reg
  const int crow0 = bm * 256 + wm + (lane >> 4) * 4;
  const int ccol0 = bn * 256 + wn + lr;
#pragma unroll
  for (int n = 0; n < 4; n++) {
    const int col = ccol0 + n * 16;
    const float bv = bias[col];
#pragma unroll
    for (int m = 0; m < 8; m++) {
#pragma unroll
      for (int r = 0; r < 4; r++) {
        float v = acc[m][n][r] + bv;
        const long row = crow0 + m * 16 + r;
        if (EPI == 0) {
          v = (v >= 0.f) ? v : 0.01f * v;
          _Float16 hi, lo; split_f16(v, hi, lo);
          _Float16* C = (_Float16*)Cout;
          C[row * (long)(2 * N) + col]     = hi;
          C[row * (long)(2 * N) + N + col] = lo;
        } else {
          ((float*)Cout)[row * (long)N + col] = v;
        }
      }
    }
  }
}

// ---------------- quat -> rotmat, write rot (d_out) + Lf (ws, f32) ----------------
__global__ void quat_rot_kernel(const float* __restrict__ q, const float* __restrict__ offs,
                                float* __restrict__ rot, float* __restrict__ Lf)
{
  const int s = blockIdx.x * 256 + threadIdx.x;
  const int j = blockIdx.y;
  const float* qp = q + (long)s * QSTR + j * 4;
  float qw = qp[0], qx = qp[1], qy = qp[2], qz = qp[3];
  float n = sqrtf(qw * qw + qx * qx + qy * qy + qz * qz);
  n = fmaxf(n, 1e-8f);
  float inv = 1.f / n;
  qw *= inv; qx *= inv; qy *= inv; qz *= inv;
  const float xx = qx * qx, yy = qy * qy, zz = qz * qz;
  const float xy = qx * qy, xz = qx * qz, yz = qy * qz;
  const float xw = qx * qw, yw = qy * qw, zw = qz * qw;
  const float r00 = 1.f - 2.f * (yy + zz), r01 = 2.f * (xy - zw), r02 = 2.f * (xz + yw);
  const float r10 = 2.f * (xy + zw), r11 = 1.f - 2.f * (xx + zz), r12 = 2.f * (yz - xw);
  const float r20 = 2.f * (xz - yw), r21 = 2.f * (yz + xw), r22 = 1.f - 2.f * (xx + yy);

  float4* ro = (float4*)(rot + ((long)s * JN + j) * 16);
  ro[0] = make_float4(r00, r01, r02, 0.f);
  ro[1] = make_float4(r10, r11, r12, 0.f);
  ro[2] = make_float4(r20, r21, r22, 0.f);
  ro[3] = make_float4(0.f, 0.f, 0.f, 1.f);

  const float tx = offs[j * 3 + 0], ty = offs[j * 3 + 1], tz = offs[j * 3 + 2];
  float* L = Lf + (long)j * 12 * B_ + s;
  L[0L * B_]  = r00; L[1L * B_]  = r01; L[2L * B_]  = r02; L[3L * B_]  = tx;
  L[4L * B_]  = r10; L[5L * B_]  = r11; L[6L * B_]  = r12; L[7L * B_]  = ty;
  L[8L * B_]  = r20; L[9L * B_]  = r21; L[10L * B_] = r22; L[11L * B_] = tz;
}

// ---------------- forward kinematics (all fp32) ----------------
struct FkParams { int par[JN]; unsigned long long childmask; };

__global__ void fk_kernel(const float* __restrict__ Lf, float* __restrict__ Gt,
                          float* __restrict__ pose, FkParams P)
{
  const int s = blockIdx.x * 256 + threadIdx.x;
  float G[12];
#pragma unroll
  for (int e = 0; e < 12; e++) G[e] = Lf[(long)e * B_ + s];
  if (P.childmask & 1ull) {
#pragma unroll
    for (int e = 0; e < 12; e++) Gt[(long)e * B_ + s] = G[e];
  }
  pose[(long)s * (JN * 3) + 0] = G[3];
  pose[(long)s * (JN * 3) + 1] = G[7];
  pose[(long)s * (JN * 3) + 2] = G[11];

  for (int j = 1; j < JN; j++) {
    const int p = P.par[j];
    float Pm[12];
    if (p == j - 1) {
#pragma unroll
      for (int e = 0; e < 12; e++) Pm[e] = G[e];
    } else {
#pragma unroll
      for (int e = 0; e < 12; e++) Pm[e] = Gt[((long)p * 12 + e) * B_ + s];
    }
    float L[12];
#pragma unroll
    for (int e = 0; e < 12; e++) L[e] = Lf[((long)j * 12 + e) * B_ + s];
#pragma unroll
    for (int r = 0; r < 3; r++) {
#pragma unroll
      for (int c = 0; c < 4; c++) {
        float v = Pm[r * 4 + 0] * L[0 * 4 + c] + Pm[r * 4 + 1] * L[1 * 4 + c]
                + Pm[r * 4 + 2] * L[2 * 4 + c];
        if (c == 3) v += Pm[r * 4 + 3];
        G[r * 4 + c] = v;
      }
    }
    if ((P.childmask >> j) & 1ull) {
#pragma unroll
      for (int e = 0; e < 12; e++) Gt[((long)j * 12 + e) * B_ + s] = G[e];
    }
    pose[(long)s * (JN * 3) + j * 3 + 0] = G[3];
    pose[(long)s * (JN * 3) + j * 3 + 1] = G[7];
    pose[(long)s * (JN * 3) + j * 3 + 2] = G[11];
  }
}

// ---------------- host: replicate np.random.default_rng(7) parents ----------------
static void compute_parents(int* par, unsigned long long* childmask)
{
  uint32_t pool[4];
  uint32_t hc = 0x43b0d7e5u;                       // INIT_A
  auto hashmix = [&hc](uint32_t v) {
    v ^= hc; hc *= 0x931e8875u; v *= hc; v ^= v >> 16; return v;
  };
  auto mix = [](uint32_t x, uint32_t y) {
    uint32_t r = 0xca01f9ddu * x - 0x4973f715u * y;
    r ^= r >> 16;
    return r;
  };
  const uint32_t entropy[1] = {7u};
  for (int i = 0; i < 4; i++) pool[i] = hashmix(i < 1 ? entropy[i] : 0u);
  for (int si = 0; si < 4; si++)
    for (int di = 0; di < 4; di++)
      if (si != di) pool[di] = mix(pool[di], hashmix(pool[si]));
  uint32_t gs[8];
  uint32_t hb = 0x8b51f9ddu;                       // INIT_B
  for (int i = 0; i < 8; i++) {
    uint32_t dv = pool[i & 3];
    dv ^= hb; hb *= 0x58f38dedu; dv *= hb; dv ^= dv >> 16;
    gs[i] = dv;
  }
  uint64_t sw0 = (uint64_t)gs[0] | ((uint64_t)gs[1] << 32);
  uint64_t sw1 = (uint64_t)gs[2] | ((uint64_t)gs[3] << 32);
  uint64_t iw0 = (uint64_t)gs[4] | ((uint64_t)gs[5] << 32);
  uint64_t iw1 = (uint64_t)gs[6] | ((uint64_t)gs[7] << 32);
  const __uint128_t MULT = (((__uint128_t)0x2360ed051fc65da4ULL) << 64) | 0x4385df649fccf645ULL;
  __uint128_t inc = ((((__uint128_t)iw0 << 64) | iw1) << 1) | 1;
  __uint128_t state = 0;
  state = state * MULT + inc;
  state += (((__uint128_t)sw0) << 64) | sw1;
  state = state * MULT + inc;
  bool has32 = false; uint32_t buf32 = 0;
  auto next64 = [&]() {
    state = state * MULT + inc;
    uint64_t hi = (uint64_t)(state >> 64), lo = (uint64_t)state;
    uint32_t rot = (uint32_t)(state >> 122);
    uint64_t x = hi ^ lo;
    return (x >> rot) | (x << ((64u - rot) & 63u));
  };
  auto next32 = [&]() -> uint32_t {
    if (has32) { has32 = false; return buf32; }
    uint64_t v = next64();
    has32 = true; buf32 = (uint32_t)(v >> 32);
    return (uint32_t)v;
  };
  par[0] = -1;
  for (int j = 1; j < JN; j++) {
    uint32_t rng = (uint32_t)(j - 1);
    if (rng == 0) { par[j] = 0; continue; }
    uint32_t rng_excl = rng + 1;
    uint64_t m = (uint64_t)next32() * (uint64_t)rng_excl;
    uint32_t leftover = (uint32_t)m;
    if (leftover < rng_excl) {
      uint32_t threshold = (uint32_t)((0x100000000ULL - rng_excl) % rng_excl);
      while (leftover < threshold) {
        m = (uint64_t)next32() * (uint64_t)rng_excl;
        leftover = (uint32_t)m;
      }
    }
    par[j] = (int)(m >> 32);
  }
  unsigned long long cm = 0;
  for (int j = 1; j < JN; j++) cm |= 1ull << par[j];
  *childmask = cm;
}

// ---------------- launch ----------------
extern "C" void kernel_launch(void* const* d_in, const int* in_sizes, int n_in,
                              void* d_out, int out_size, void* d_ws, size_t ws_size,
                              hipStream_t stream)
{
  const float* in_seq = (const float*)d_in[0];
  const float* w1 = (const float*)d_in[1];
  const float* b1 = (const float*)d_in[2];
  const float* w2 = (const float*)d_in[3];
  const float* b2 = (const float*)d_in[4];
  const float* w3 = (const float*)d_in[5];
  const float* b3 = (const float*)d_in[6];
  const float* w4 = (const float*)d_in[7];
  const float* b4 = (const float*)d_in[8];
  const float* offs = (const float*)d_in[9];

  char* pR1 = (char*)d_ws;
  char* pR2 = pR1 + 35390464;
  char* pR3 = pR2 + 134217728;
  _Float16* x2  = (_Float16*)pR1;
  _Float16* w1f = (_Float16*)(pR1 + 25165824);
  _Float16* w2f = (_Float16*)(pR1 + 25165824 + 786432);
  _Float16* w3f = (_Float16*)(pR1 + 25165824 + 786432 + 4194304);
  _Float16* w4f = (_Float16*)(pR1 + 25165824 + 786432 + 2 * 4194304);
  float*    b4p = (float*)(pR1 + 25165824 + 786432 + 2 * 4194304 + 1048576);
  float*    q   = (float*)pR1;            // overwrites x2/w1f/w2f/w3f only
  _Float16* h1  = (_Float16*)pR2;
  _Float16* h3  = (_Float16*)pR2;
  float*    Gt  = (float*)pR2;
  _Float16* h2  = (_Float16*)pR3;
  float*    Lf  = (float*)pR3;

  float* pose = (float*)d_out;                        // [B_,57,3]
  float* rot  = (float*)d_out + (long)B_ * JN * 3;    // [B_,57,4,4]

  // prep
  prep_x2_kernel<<<(B_ * 192) / 256, 256, 0, stream>>>(in_seq, x2);
  prep_w2_kernel<<<(1024 * 192) / 256, 256, 0, stream>>>(w1, w1f, 171, 192, 1024);
  prep_w2_kernel<<<(1024 * 1024) / 256, 256, 0, stream>>>(w2, w2f, 1024, 1024, 1024);
  prep_w2_kernel<<<(1024 * 1024) / 256, 256, 0, stream>>>(w3, w3f, 1024, 1024, 1024);
  prep_w2_kernel<<<(256 * 1024) / 256, 256, 0, stream>>>(w4, w4f, 1024, 1024, 228);
  prep_b4_kernel<<<1, 256, 0, stream>>>(b4, b4p);

  // MLP (split-f16, virtual 3K)
  gemm_hl<0><<<(B_ / 128) * (1024 / 128), 256, 0, stream>>>(x2, w1f, b1, h1, B_, 1024, 192);
  gemm256<0><<<(B_ / 256) * (1024 / 256), 512, 0, stream>>>(h1, w2f, b2, h2, B_, 1024, 1024);
  gemm256<0><<<(B_ / 256) * (1024 / 256), 512, 0, stream>>>(h2, w3f, b3, h3, B_, 1024, 1024);
  gemm256<1><<<(B_ / 256) * (QSTR / 256), 512, 0, stream>>>(h3, w4f, b4p, q, B_, QSTR, 1024);

  // epilogue
  quat_rot_kernel<<<dim3(B_ / 256, JN), 256, 0, stream>>>(q, offs, rot, Lf);

  FkParams P;
  compute_parents(P.par, &P.childmask);
  fk_kernel<<<B_ / 256, 256, 0, stream>>>(Lf, Gt, pose, P);
}

// Round 8
// 825.988 us; speedup vs baseline: 1.0888x; 1.0888x over previous
//
#include <hip/hip_runtime.h>
#include <hip/hip_bf16.h>
#include <stdint.h>

#define B_   32768
#define JN   57
#define QSTR 256      // q row stride (228 padded to 256)

typedef _Float16 f16x8 __attribute__((ext_vector_type(8)));
typedef float    f32x4 __attribute__((ext_vector_type(4)));

__device__ __forceinline__ void split_f16(float v, _Float16& hi, _Float16& lo) {
  hi = (_Float16)v;
  lo = (_Float16)(v - (float)hi);
}

// ---------------- prep kernels ----------------
__global__ void prep_x2_kernel(const float* __restrict__ x, _Float16* __restrict__ xp) {
  long i = (long)blockIdx.x * 256 + threadIdx.x;   // over B_*192
  int row = (int)(i / 192), col = (int)(i % 192);
  float v = (col < 171) ? x[(long)row * 171 + col] : 0.f;
  _Float16 hi, lo; split_f16(v, hi, lo);
  xp[(long)row * 384 + col]       = hi;
  xp[(long)row * 384 + 192 + col] = lo;
}

__global__ void prep_w2_kernel(const float* __restrict__ w, _Float16* __restrict__ wf,
                               int Ksrc, int Kpad, int Nsrc) {
  long i = (long)blockIdx.x * 256 + threadIdx.x;   // over Ndst*Kpad
  int n = (int)(i / Kpad), k = (int)(i % Kpad);
  float v = (k < Ksrc && n < Nsrc) ? w[(long)k * Nsrc + n] : 0.f;
  _Float16 hi, lo; split_f16(v, hi, lo);
  wf[(long)n * (2 * Kpad) + k]        = hi;
  wf[(long)n * (2 * Kpad) + Kpad + k] = lo;
}

__global__ void prep_b4_kernel(const float* __restrict__ b, float* __restrict__ bp) {
  int i = threadIdx.x;  // 256 threads
  bp[i] = (i < 228) ? b[i] : 0.f;
}

// ---------------- 128² split-f16 GEMM (m97 structure) — layer 1 only ----------------
template<int EPI>
__global__ __launch_bounds__(256)
void gemm_hl(const _Float16* __restrict__ A, const _Float16* __restrict__ Bt,
             const float* __restrict__ bias, void* __restrict__ Cout,
             int M, int N, int Kp)
{
  __shared__ __align__(16) _Float16 As[128 * 64];
  __shared__ __align__(16) _Float16 Bs[128 * 64];
  const int lda = 2 * Kp;
  const int T = Kp >> 6;
  const int tiles_n = N >> 7;
  const int cpx  = gridDim.x >> 3;
  const int virt = (blockIdx.x & 7) * cpx + (blockIdx.x >> 3);
  const int bm = virt / tiles_n;
  const int bn = virt % tiles_n;
  const int tid  = threadIdx.x;
  const int wave = tid >> 6;
  const int lane = tid & 63;

  const int srow = wave * 8 + (lane >> 3);
  const int scol = (((lane & 7) ^ (lane >> 3)) * 8);
  const long abase = (long)bm * 128;
  const long bbase = (long)bn * 128;

  f32x4 acc[4][4] = {};

  const int wm = (wave >> 1) * 64;
  const int wn = (wave & 1) * 64;
  const int lr = lane & 15;
  const int ch0 = (((lane >> 4) ^ (lane & 7)) * 8);
  const int ch1 = (((4 + (lane >> 4)) ^ (lane & 7)) * 8);

  for (int ph = 0; ph < 3; ++ph) {
    const int aoff = (ph == 2) ? Kp : 0;
    const int boff = (ph == 1) ? Kp : 0;
    for (int u = 0; u < T; ++u) {
#pragma unroll
      for (int i = 0; i < 4; i++) {
        const _Float16* asrc = A  + (abase + i * 32 + srow) * (long)lda + (aoff + u * 64 + scol);
        const _Float16* bsrc = Bt + (bbase + i * 32 + srow) * (long)lda + (boff + u * 64 + scol);
        __builtin_amdgcn_global_load_lds(
            (const __attribute__((address_space(1))) void*)asrc,
            (__attribute__((address_space(3))) void*)(As + (i * 256 + wave * 64) * 8),
            16, 0, 0);
        __builtin_amdgcn_global_load_lds(
            (const __attribute__((address_space(1))) void*)bsrc,
            (__attribute__((address_space(3))) void*)(Bs + (i * 256 + wave * 64) * 8),
            16, 0, 0);
      }
      __syncthreads();

#pragma unroll
      for (int ks = 0; ks < 2; ks++) {
        const int ch = ks ? ch1 : ch0;
        f16x8 af[4], bfr[4];
#pragma unroll
        for (int m = 0; m < 4; m++)
          af[m] = *(const f16x8*)(As + (wm + m * 16 + lr) * 64 + ch);
#pragma unroll
        for (int n = 0; n < 4; n++)
          bfr[n] = *(const f16x8*)(Bs + (wn + n * 16 + lr) * 64 + ch);
#pragma unroll
        for (int m = 0; m < 4; m++)
#pragma unroll
          for (int n = 0; n < 4; n++)
            acc[m][n] = __builtin_amdgcn_mfma_f32_16x16x32_f16(af[m], bfr[n], acc[m][n], 0, 0, 0);
      }
      __syncthreads();
    }
  }

  const int crow0 = bm * 128 + wm + (lane >> 4) * 4;
  const int ccol0 = bn * 128 + wn + lr;
#pragma unroll
  for (int n = 0; n < 4; n++) {
    const int col = ccol0 + n * 16;
    const float bv = bias[col];
#pragma unroll
    for (int m = 0; m < 4; m++) {
#pragma unroll
      for (int r = 0; r < 4; r++) {
        float v = acc[m][n][r] + bv;
        const long row = crow0 + m * 16 + r;
        if (EPI == 0) {
          v = (v >= 0.f) ? v : 0.01f * v;
          _Float16 hi, lo; split_f16(v, hi, lo);
          _Float16* C = (_Float16*)Cout;
          C[row * (long)(2 * N) + col]     = hi;
          C[row * (long)(2 * N) + N + col] = lo;
        } else {
          ((float*)Cout)[row * (long)N + col] = v;
        }
      }
    }
  }
}

// ---------------- 256² 8-phase split-f16 GEMM — deep-prefetch schedule ----------------
// 512 thr = 8 waves (2M x 4N), per-wave 128x64 out. BK=64, 2 LDS slots (128KB).
// Iter i: P1-P4 compute tile a=2i from S0, P5-P8 compute b=2i+1 from S1.
// Staging: tile b's A (4 loads) at P1, B (4) at P2 -> vmcnt(0) at END of P4
// (2-3 phase issue->wait distance covers HBM latency; B is L2-warm).
// Tile c=2i+2 -> S0: A at P5, B at P6, waited at end of P8. WAR-safe: the
// slot's previous readers all passed the preceding slot-transition barrier.
// Phase = {ds_reads; stage-issue; [vmcnt]; barrier; 16 MFMA; [end-barrier only
// at P4/P8 — the only stage-WAR transitions]}. 10 barriers/iter (was 16).
template<int EPI>
__global__ __launch_bounds__(512, 2)
void gemm256(const _Float16* __restrict__ Ag, const _Float16* __restrict__ Bt,
             const float* __restrict__ bias, void* __restrict__ Cout,
             int M, int N, int Kp)
{
  __shared__ __align__(16) _Float16 As[2][256 * 64];
  __shared__ __align__(16) _Float16 Bs[2][256 * 64];
  const int lda = 2 * Kp;
  const int T  = Kp >> 6;
  const int NT = 3 * T;
  const int NI = NT >> 1;
  const int tiles_n = N >> 8;
  const int cpx  = gridDim.x >> 3;
  const int virt = (blockIdx.x & 7) * cpx + (blockIdx.x >> 3);
  const int bm = virt / tiles_n;
  const int bn = virt % tiles_n;
  const int tid  = threadIdx.x;
  const int wid  = tid >> 6;
  const int lane = tid & 63;

  const long abase = (long)bm * 256;
  const long bbase = (long)bn * 256;
  const int scol = (((lane & 7) ^ ((tid >> 3) & 7)) * 8);

  const int wm = (wid >> 2) * 128;
  const int wn = (wid & 3) * 64;
  const int lr = lane & 15;

  f32x4 acc[8][4] = {};

  auto stageA = [&](int t, int s, int h) {
    const int ph = t / T, u = t - ph * T;
    const long ko = ((ph == 2) ? (long)Kp : 0) + u * 64 + scol;
    const _Float16* src = Ag + (abase + h * 128 + (tid >> 3)) * (long)lda + ko;
    const _Float16* dst = &As[s][h * 8192 + tid * 8];
    __builtin_amdgcn_global_load_lds(
        (const __attribute__((address_space(1))) void*)src,
        (__attribute__((address_space(3))) void*)dst, 16, 0, 0);
    __builtin_amdgcn_global_load_lds(
        (const __attribute__((address_space(1))) void*)(src + 64 * (long)lda),
        (__attribute__((address_space(3))) void*)(dst + 4096), 16, 0, 0);
  };
  auto stageB = [&](int t, int s, int h) {
    const int ph = t / T, u = t - ph * T;
    const long ko = ((ph == 1) ? (long)Kp : 0) + u * 64 + scol;
    const _Float16* src = Bt + (bbase + h * 128 + (tid >> 3)) * (long)lda + ko;
    const _Float16* dst = &Bs[s][h * 8192 + tid * 8];
    __builtin_amdgcn_global_load_lds(
        (const __attribute__((address_space(1))) void*)src,
        (__attribute__((address_space(3))) void*)dst, 16, 0, 0);
    __builtin_amdgcn_global_load_lds(
        (const __attribute__((address_space(1))) void*)(src + 64 * (long)lda),
        (__attribute__((address_space(3))) void*)(dst + 4096), 16, 0, 0);
  };

#define FRAG_READS(slot, mh, ks)                                                  \
    const int ch = (((ks) * 4 + (lane >> 4)) ^ (lane & 7)) * 8;                   \
    f16x8 af[4], bfr[4];                                                          \
    _Pragma("unroll")                                                             \
    for (int mi = 0; mi < 4; ++mi)                                                \
      af[mi] = *(const f16x8*)&As[slot][(wm + (mh) * 64 + mi * 16 + lr) * 64 + ch]; \
    _Pragma("unroll")                                                             \
    for (int n = 0; n < 4; ++n)                                                   \
      bfr[n] = *(const f16x8*)&Bs[slot][(wn + n * 16 + lr) * 64 + ch];

#define MFMA16(mh)                                                                \
    __builtin_amdgcn_s_setprio(1);                                                \
    _Pragma("unroll")                                                             \
    for (int mi = 0; mi < 4; ++mi)                                                \
      _Pragma("unroll")                                                           \
      for (int n = 0; n < 4; ++n)                                                 \
        acc[(mh) * 4 + mi][n] = __builtin_amdgcn_mfma_f32_16x16x32_f16(           \
            af[mi], bfr[n], acc[(mh) * 4 + mi][n], 0, 0, 0);                      \
    __builtin_amdgcn_s_setprio(0);

  // WAITV/ENDBAR are compile-time; STAGE via __VA_ARGS__
#define PH(slot, mh, ks, WAITV, ENDBAR, ...)                                      \
  do {                                                                            \
    FRAG_READS(slot, mh, ks)                                                      \
    __VA_ARGS__;                                                                  \
    if (WAITV) asm volatile("s_waitcnt vmcnt(0)" ::: "memory");                   \
    __builtin_amdgcn_s_barrier();                                                 \
    MFMA16(mh)                                                                    \
    if (ENDBAR) __builtin_amdgcn_s_barrier();                                     \
  } while (0)

  // prologue: full tile 0 -> S0
  stageA(0, 0, 0); stageA(0, 0, 1); stageB(0, 0, 0); stageB(0, 0, 1);
  asm volatile("s_waitcnt vmcnt(0)" ::: "memory");
  __builtin_amdgcn_s_barrier();

  for (int i = 0; i < NI; ++i) {
    const int b = 2 * i + 1;
    const int c = (2 * i + 2 < NT) ? 2 * i + 2 : 0;   // tail: harmless re-stage
    PH(0, 0, 0, 0, 0, stageA(b, 1, 0); stageA(b, 1, 1));
    PH(0, 1, 0, 0, 0, stageB(b, 1, 0); stageB(b, 1, 1));
    PH(0, 0, 1, 0, 0, );
    PH(0, 1, 1, 1, 1, );
    PH(1, 0, 0, 0, 0, stageA(c, 0, 0); stageA(c, 0, 1));
    PH(1, 1, 0, 0, 0, stageB(c, 0, 0); stageB(c, 0, 1));
    PH(1, 0, 1, 0, 0, );
    PH(1, 1, 1, 1, 1, );
  }
  asm volatile("s_waitcnt vmcnt(0)" ::: "memory");

#undef PH
#undef FRAG_READS
#undef MFMA16

  // epilogue: C/D layout col=lane&15, row=(lane>>4)*4+reg
  const int crow0 = bm * 256 + wm + (lane >> 4) * 4;
  const int ccol0 = bn * 256 + wn + lr;
#pragma unroll
  for (int n = 0; n < 4; n++) {
    const int col = ccol0 + n * 16;
    const float bv = bias[col];
#pragma unroll
    for (int m = 0; m < 8; m++) {
#pragma unroll
      for (int r = 0; r < 4; r++) {
        float v = acc[m][n][r] + bv;
        const long row = crow0 + m * 16 + r;
        if (EPI == 0) {
          v = (v >= 0.f) ? v : 0.01f * v;
          _Float16 hi, lo; split_f16(v, hi, lo);
          _Float16* C = (_Float16*)Cout;
          C[row * (long)(2 * N) + col]     = hi;
          C[row * (long)(2 * N) + N + col] = lo;
        } else {
          ((float*)Cout)[row * (long)N + col] = v;
        }
      }
    }
  }
}

// ---------------- quat -> rotmat, write rot (d_out) + Lf (ws, f32) ----------------
__global__ void quat_rot_kernel(const float* __restrict__ q, const float* __restrict__ offs,
                                float* __restrict__ rot, float* __restrict__ Lf)
{
  const int s = blockIdx.x * 256 + threadIdx.x;
  const int j = blockIdx.y;
  const float* qp = q + (long)s * QSTR + j * 4;
  float qw = qp[0], qx = qp[1], qy = qp[2], qz = qp[3];
  float n = sqrtf(qw * qw + qx * qx + qy * qy + qz * qz);
  n = fmaxf(n, 1e-8f);
  float inv = 1.f / n;
  qw *= inv; qx *= inv; qy *= inv; qz *= inv;
  const float xx = qx * qx, yy = qy * qy, zz = qz * qz;
  const float xy = qx * qy, xz = qx * qz, yz = qy * qz;
  const float xw = qx * qw, yw = qy * qw, zw = qz * qw;
  const float r00 = 1.f - 2.f * (yy + zz), r01 = 2.f * (xy - zw), r02 = 2.f * (xz + yw);
  const float r10 = 2.f * (xy + zw), r11 = 1.f - 2.f * (xx + zz), r12 = 2.f * (yz - xw);
  const float r20 = 2.f * (xz - yw), r21 = 2.f * (yz + xw), r22 = 1.f - 2.f * (xx + yy);

  float4* ro = (float4*)(rot + ((long)s * JN + j) * 16);
  ro[0] = make_float4(r00, r01, r02, 0.f);
  ro[1] = make_float4(r10, r11, r12, 0.f);
  ro[2] = make_float4(r20, r21, r22, 0.f);
  ro[3] = make_float4(0.f, 0.f, 0.f, 1.f);

  const float tx = offs[j * 3 + 0], ty = offs[j * 3 + 1], tz = offs[j * 3 + 2];
  float* L = Lf + (long)j * 12 * B_ + s;
  L[0L * B_]  = r00; L[1L * B_]  = r01; L[2L * B_]  = r02; L[3L * B_]  = tx;
  L[4L * B_]  = r10; L[5L * B_]  = r11; L[6L * B_]  = r12; L[7L * B_]  = ty;
  L[8L * B_]  = r20; L[9L * B_]  = r21; L[10L * B_] = r22; L[11L * B_] = tz;
}

// ---------------- forward kinematics (all fp32) ----------------
struct FkParams { int par[JN]; unsigned long long childmask; };

__global__ void fk_kernel(const float* __restrict__ Lf, float* __restrict__ Gt,
                          float* __restrict__ pose, FkParams P)
{
  const int s = blockIdx.x * 256 + threadIdx.x;
  float G[12];
#pragma unroll
  for (int e = 0; e < 12; e++) G[e] = Lf[(long)e * B_ + s];
  if (P.childmask & 1ull) {
#pragma unroll
    for (int e = 0; e < 12; e++) Gt[(long)e * B_ + s] = G[e];
  }
  pose[(long)s * (JN * 3) + 0] = G[3];
  pose[(long)s * (JN * 3) + 1] = G[7];
  pose[(long)s * (JN * 3) + 2] = G[11];

  for (int j = 1; j < JN; j++) {
    const int p = P.par[j];
    float Pm[12];
    if (p == j - 1) {
#pragma unroll
      for (int e = 0; e < 12; e++) Pm[e] = G[e];
    } else {
#pragma unroll
      for (int e = 0; e < 12; e++) Pm[e] = Gt[((long)p * 12 + e) * B_ + s];
    }
    float L[12];
#pragma unroll
    for (int e = 0; e < 12; e++) L[e] = Lf[((long)j * 12 + e) * B_ + s];
#pragma unroll
    for (int r = 0; r < 3; r++) {
#pragma unroll
      for (int c = 0; c < 4; c++) {
        float v = Pm[r * 4 + 0] * L[0 * 4 + c] + Pm[r * 4 + 1] * L[1 * 4 + c]
                + Pm[r * 4 + 2] * L[2 * 4 + c];
        if (c == 3) v += Pm[r * 4 + 3];
        G[r * 4 + c] = v;
      }
    }
    if ((P.childmask >> j) & 1ull) {
#pragma unroll
      for (int e = 0; e < 12; e++) Gt[((long)j * 12 + e) * B_ + s] = G[e];
    }
    pose[(long)s * (JN * 3) + j * 3 + 0] = G[3];
    pose[(long)s * (JN * 3) + j * 3 + 1] = G[7];
    pose[(long)s * (JN * 3) + j * 3 + 2] = G[11];
  }
}

// ---------------- host: replicate np.random.default_rng(7) parents ----------------
static void compute_parents(int* par, unsigned long long* childmask)
{
  uint32_t pool[4];
  uint32_t hc = 0x43b0d7e5u;                       // INIT_A
  auto hashmix = [&hc](uint32_t v) {
    v ^= hc; hc *= 0x931e8875u; v *= hc; v ^= v >> 16; return v;
  };
  auto mix = [](uint32_t x, uint32_t y) {
    uint32_t r = 0xca01f9ddu * x - 0x4973f715u * y;
    r ^= r >> 16;
    return r;
  };
  const uint32_t entropy[1] = {7u};
  for (int i = 0; i < 4; i++) pool[i] = hashmix(i < 1 ? entropy[i] : 0u);
  for (int si = 0; si < 4; si++)
    for (int di = 0; di < 4; di++)
      if (si != di) pool[di] = mix(pool[di], hashmix(pool[si]));
  uint32_t gs[8];
  uint32_t hb = 0x8b51f9ddu;                       // INIT_B
  for (int i = 0; i < 8; i++) {
    uint32_t dv = pool[i & 3];
    dv ^= hb; hb *= 0x58f38dedu; dv *= hb; dv ^= dv >> 16;
    gs[i] = dv;
  }
  uint64_t sw0 = (uint64_t)gs[0] | ((uint64_t)gs[1] << 32);
  uint64_t sw1 = (uint64_t)gs[2] | ((uint64_t)gs[3] << 32);
  uint64_t iw0 = (uint64_t)gs[4] | ((uint64_t)gs[5] << 32);
  uint64_t iw1 = (uint64_t)gs[6] | ((uint64_t)gs[7] << 32);
  const __uint128_t MULT = (((__uint128_t)0x2360ed051fc65da4ULL) << 64) | 0x4385df649fccf645ULL;
  __uint128_t inc = ((((__uint128_t)iw0 << 64) | iw1) << 1) | 1;
  __uint128_t state = 0;
  state = state * MULT + inc;
  state += (((__uint128_t)sw0) << 64) | sw1;
  state = state * MULT + inc;
  bool has32 = false; uint32_t buf32 = 0;
  auto next64 = [&]() {
    state = state * MULT + inc;
    uint64_t hi = (uint64_t)(state >> 64), lo = (uint64_t)state;
    uint32_t rot = (uint32_t)(state >> 122);
    uint64_t x = hi ^ lo;
    return (x >> rot) | (x << ((64u - rot) & 63u));
  };
  auto next32 = [&]() -> uint32_t {
    if (has32) { has32 = false; return buf32; }
    uint64_t v = next64();
    has32 = true; buf32 = (uint32_t)(v >> 32);
    return (uint32_t)v;
  };
  par[0] = -1;
  for (int j = 1; j < JN; j++) {
    uint32_t rng = (uint32_t)(j - 1);
    if (rng == 0) { par[j] = 0; continue; }
    uint32_t rng_excl = rng + 1;
    uint64_t m = (uint64_t)next32() * (uint64_t)rng_excl;
    uint32_t leftover = (uint32_t)m;
    if (leftover < rng_excl) {
      uint32_t threshold = (uint32_t)((0x100000000ULL - rng_excl) % rng_excl);
      while (leftover < threshold) {
        m = (uint64_t)next32() * (uint64_t)rng_excl;
        leftover = (uint32_t)m;
      }
    }
    par[j] = (int)(m >> 32);
  }
  unsigned long long cm = 0;
  for (int j = 1; j < JN; j++) cm |= 1ull << par[j];
  *childmask = cm;
}

// ---------------- launch ----------------
extern "C" void kernel_launch(void* const* d_in, const int* in_sizes, int n_in,
                              void* d_out, int out_size, void* d_ws, size_t ws_size,
                              hipStream_t stream)
{
  const float* in_seq = (const float*)d_in[0];
  const float* w1 = (const float*)d_in[1];
  const float* b1 = (const float*)d_in[2];
  const float* w2 = (const float*)d_in[3];
  const float* b2 = (const float*)d_in[4];
  const float* w3 = (const float*)d_in[5];
  const float* b3 = (const float*)d_in[6];
  const float* w4 = (const float*)d_in[7];
  const float* b4 = (const float*)d_in[8];
  const float* offs = (const float*)d_in[9];

  char* pR1 = (char*)d_ws;
  char* pR2 = pR1 + 35390464;
  char* pR3 = pR2 + 134217728;
  _Float16* x2  = (_Float16*)pR1;
  _Float16* w1f = (_Float16*)(pR1 + 25165824);
  _Float16* w2f = (_Float16*)(pR1 + 25165824 + 786432);
  _Float16* w3f = (_Float16*)(pR1 + 25165824 + 786432 + 4194304);
  _Float16* w4f = (_Float16*)(pR1 + 25165824 + 786432 + 2 * 4194304);
  float*    b4p = (float*)(pR1 + 25165824 + 786432 + 2 * 4194304 + 1048576);
  float*    q   = (float*)pR1;            // overwrites x2/w1f/w2f/w3f only
  _Float16* h1  = (_Float16*)pR2;
  _Float16* h3  = (_Float16*)pR2;
  float*    Gt  = (float*)pR2;
  _Float16* h2  = (_Float16*)pR3;
  float*    Lf  = (float*)pR3;

  float* pose = (float*)d_out;                        // [B_,57,3]
  float* rot  = (float*)d_out + (long)B_ * JN * 3;    // [B_,57,4,4]

  // prep
  prep_x2_kernel<<<(B_ * 192) / 256, 256, 0, stream>>>(in_seq, x2);
  prep_w2_kernel<<<(1024 * 192) / 256, 256, 0, stream>>>(w1, w1f, 171, 192, 1024);
  prep_w2_kernel<<<(1024 * 1024) / 256, 256, 0, stream>>>(w2, w2f, 1024, 1024, 1024);
  prep_w2_kernel<<<(1024 * 1024) / 256, 256, 0, stream>>>(w3, w3f, 1024, 1024, 1024);
  prep_w2_kernel<<<(256 * 1024) / 256, 256, 0, stream>>>(w4, w4f, 1024, 1024, 228);
  prep_b4_kernel<<<1, 256, 0, stream>>>(b4, b4p);

  // MLP (split-f16, virtual 3K)
  gemm_hl<0><<<(B_ / 128) * (1024 / 128), 256, 0, stream>>>(x2, w1f, b1, h1, B_, 1024, 192);
  gemm256<0><<<(B_ / 256) * (1024 / 256), 512, 0, stream>>>(h1, w2f, b2, h2, B_, 1024, 1024);
  gemm256<0><<<(B_ / 256) * (1024 / 256), 512, 0, stream>>>(h2, w3f, b3, h3, B_, 1024, 1024);
  gemm256<1><<<(B_ / 256) * (QSTR / 256), 512, 0, stream>>>(h3, w4f, b4p, q, B_, QSTR, 1024);

  // epilogue
  quat_rot_kernel<<<dim3(B_ / 256, JN), 256, 0, stream>>>(q, offs, rot, Lf);

  FkParams P;
  compute_parents(P.par, &P.childmask);
  fk_kernel<<<B_ / 256, 256, 0, stream>>>(Lf, Gt, pose, P);
}

// Round 9
// 771.109 us; speedup vs baseline: 1.1663x; 1.0712x over previous
//
#include <hip/hip_runtime.h>
#include <hip/hip_bf16.h>
#include <stdint.h>

#define B_   32768
#define JN   57
#define QSTR 256      // q row stride (228 padded to 256)

typedef _Float16 f16x8 __attribute__((ext_vector_type(8)));
typedef float    f32x4 __attribute__((ext_vector_type(4)));

__device__ __forceinline__ void split_f16(float v, _Float16& hi, _Float16& lo) {
  hi = (_Float16)v;
  lo = (_Float16)(v - (float)hi);
}

// ---------------- prep kernels ----------------
__global__ void prep_x2_kernel(const float* __restrict__ x, _Float16* __restrict__ xp) {
  long i = (long)blockIdx.x * 256 + threadIdx.x;   // over B_*192
  int row = (int)(i / 192), col = (int)(i % 192);
  float v = (col < 171) ? x[(long)row * 171 + col] : 0.f;
  _Float16 hi, lo; split_f16(v, hi, lo);
  xp[(long)row * 384 + col]       = hi;
  xp[(long)row * 384 + 192 + col] = lo;
}

__global__ void prep_w2_kernel(const float* __restrict__ w, _Float16* __restrict__ wf,
                               int Ksrc, int Kpad, int Nsrc) {
  long i = (long)blockIdx.x * 256 + threadIdx.x;   // over Ndst*Kpad
  int n = (int)(i / Kpad), k = (int)(i % Kpad);
  float v = (k < Ksrc && n < Nsrc) ? w[(long)k * Nsrc + n] : 0.f;
  _Float16 hi, lo; split_f16(v, hi, lo);
  wf[(long)n * (2 * Kpad) + k]        = hi;
  wf[(long)n * (2 * Kpad) + Kpad + k] = lo;
}

__global__ void prep_b4_kernel(const float* __restrict__ b, float* __restrict__ bp) {
  int i = threadIdx.x;  // 256 threads
  bp[i] = (i < 228) ? b[i] : 0.f;
}

// ---------------- 128² split-f16 GEMM (m97 structure) — layer 1 only ----------------
template<int EPI>
__global__ __launch_bounds__(256)
void gemm_hl(const _Float16* __restrict__ A, const _Float16* __restrict__ Bt,
             const float* __restrict__ bias, void* __restrict__ Cout,
             int M, int N, int Kp)
{
  __shared__ __align__(16) _Float16 As[128 * 64];
  __shared__ __align__(16) _Float16 Bs[128 * 64];
  const int lda = 2 * Kp;
  const int T = Kp >> 6;
  const int tiles_n = N >> 7;
  const int cpx  = gridDim.x >> 3;
  const int virt = (blockIdx.x & 7) * cpx + (blockIdx.x >> 3);
  const int bm = virt / tiles_n;
  const int bn = virt % tiles_n;
  const int tid  = threadIdx.x;
  const int wave = tid >> 6;
  const int lane = tid & 63;

  const int srow = wave * 8 + (lane >> 3);
  const int scol = (((lane & 7) ^ (lane >> 3)) * 8);
  const long abase = (long)bm * 128;
  const long bbase = (long)bn * 128;

  f32x4 acc[4][4] = {};

  const int wm = (wave >> 1) * 64;
  const int wn = (wave & 1) * 64;
  const int lr = lane & 15;
  const int ch0 = (((lane >> 4) ^ (lane & 7)) * 8);
  const int ch1 = (((4 + (lane >> 4)) ^ (lane & 7)) * 8);

  for (int ph = 0; ph < 3; ++ph) {
    const int aoff = (ph == 2) ? Kp : 0;
    const int boff = (ph == 1) ? Kp : 0;
    for (int u = 0; u < T; ++u) {
#pragma unroll
      for (int i = 0; i < 4; i++) {
        const _Float16* asrc = A  + (abase + i * 32 + srow) * (long)lda + (aoff + u * 64 + scol);
        const _Float16* bsrc = Bt + (bbase + i * 32 + srow) * (long)lda + (boff + u * 64 + scol);
        __builtin_amdgcn_global_load_lds(
            (const __attribute__((address_space(1))) void*)asrc,
            (__attribute__((address_space(3))) void*)(As + (i * 256 + wave * 64) * 8),
            16, 0, 0);
        __builtin_amdgcn_global_load_lds(
            (const __attribute__((address_space(1))) void*)bsrc,
            (__attribute__((address_space(3))) void*)(Bs + (i * 256 + wave * 64) * 8),
            16, 0, 0);
      }
      __syncthreads();

#pragma unroll
      for (int ks = 0; ks < 2; ks++) {
        const int ch = ks ? ch1 : ch0;
        f16x8 af[4], bfr[4];
#pragma unroll
        for (int m = 0; m < 4; m++)
          af[m] = *(const f16x8*)(As + (wm + m * 16 + lr) * 64 + ch);
#pragma unroll
        for (int n = 0; n < 4; n++)
          bfr[n] = *(const f16x8*)(Bs + (wn + n * 16 + lr) * 64 + ch);
#pragma unroll
        for (int m = 0; m < 4; m++)
#pragma unroll
          for (int n = 0; n < 4; n++)
            acc[m][n] = __builtin_amdgcn_mfma_f32_16x16x32_f16(af[m], bfr[n], acc[m][n], 0, 0, 0);
      }
      __syncthreads();
    }
  }

  const int crow0 = bm * 128 + wm + (lane >> 4) * 4;
  const int ccol0 = bn * 128 + wn + lr;
#pragma unroll
  for (int n = 0; n < 4; n++) {
    const int col = ccol0 + n * 16;
    const float bv = bias[col];
#pragma unroll
    for (int m = 0; m < 4; m++) {
#pragma unroll
      for (int r = 0; r < 4; r++) {
        float v = acc[m][n][r] + bv;
        const long row = crow0 + m * 16 + r;
        if (EPI == 0) {
          v = (v >= 0.f) ? v : 0.01f * v;
          _Float16 hi, lo; split_f16(v, hi, lo);
          _Float16* C = (_Float16*)Cout;
          C[row * (long)(2 * N) + col]     = hi;
          C[row * (long)(2 * N) + N + col] = lo;
        } else {
          ((float*)Cout)[row * (long)N + col] = v;
        }
      }
    }
  }
}

// ---------------- 256² 4-phase split-f16 GEMM — B-dedup schedule ----------------
// 512 thr = 8 waves (2M x 4N), per-wave 128x64 out. BK=64, 2 LDS slots (128KB).
// LDS-BW analysis (R8 post-mortem): old 8-phase re-read bfr[4] for each m-half
// -> 64 b128/wave/iter; LDS port (256B/cyc/CU) was the critical path. New:
// 4 phases/iter, each = all 8 m-frags x one ks: reads af[8]+bfr[4]=12 b128 for
// 32 MFMA -> 48 b128/wave/iter (-25% LDS reads).
// Sync ledger (per wave, in-order vmcnt):  prologue issues a(8).
//  Q1: stage bA(4) [out 12] ; vmcnt(4) [a landed] ; bar ; reads S0 ks0 ; MFMA
//  Q2: stage bB(4) [out  8] ;                       bar ; reads S0 ks1 ; MFMA
//  Q3: stage cA(4) [out 12] ; vmcnt(4) [b landed] ; bar ; reads S1 ks0 ; MFMA
//  Q4: stage cB(4) [out  8] ;                       bar ; reads S1 ks1 ; MFMA
// WAR (e.g. Q3's cA->S0 vs Q2's S0 reads): separated by Q2's barrier + DMA
// return latency (>=200cyc) >> ds_read latency — m201's accepted hazard class.
template<int EPI>
__global__ __launch_bounds__(512, 2)
void gemm256(const _Float16* __restrict__ Ag, const _Float16* __restrict__ Bt,
             const float* __restrict__ bias, void* __restrict__ Cout,
             int M, int N, int Kp)
{
  __shared__ __align__(16) _Float16 As[2][256 * 64];
  __shared__ __align__(16) _Float16 Bs[2][256 * 64];
  const int lda = 2 * Kp;
  const int T  = Kp >> 6;
  const int NT = 3 * T;
  const int NI = NT >> 1;
  const int tiles_n = N >> 8;
  const int cpx  = gridDim.x >> 3;
  const int virt = (blockIdx.x & 7) * cpx + (blockIdx.x >> 3);
  const int bm = virt / tiles_n;
  const int bn = virt % tiles_n;
  const int tid  = threadIdx.x;
  const int wid  = tid >> 6;
  const int lane = tid & 63;

  const long abase = (long)bm * 256;
  const long bbase = (long)bn * 256;
  const int scol = (((lane & 7) ^ ((tid >> 3) & 7)) * 8);

  const int wm = (wid >> 2) * 128;
  const int wn = (wid & 3) * 64;
  const int lr = lane & 15;

  f32x4 acc[8][4] = {};

  auto stageA = [&](int t, int s, int h) {
    const int ph = t / T, u = t - ph * T;
    const long ko = ((ph == 2) ? (long)Kp : 0) + u * 64 + scol;
    const _Float16* src = Ag + (abase + h * 128 + (tid >> 3)) * (long)lda + ko;
    const _Float16* dst = &As[s][h * 8192 + tid * 8];
    __builtin_amdgcn_global_load_lds(
        (const __attribute__((address_space(1))) void*)src,
        (__attribute__((address_space(3))) void*)dst, 16, 0, 0);
    __builtin_amdgcn_global_load_lds(
        (const __attribute__((address_space(1))) void*)(src + 64 * (long)lda),
        (__attribute__((address_space(3))) void*)(dst + 4096), 16, 0, 0);
  };
  auto stageB = [&](int t, int s, int h) {
    const int ph = t / T, u = t - ph * T;
    const long ko = ((ph == 1) ? (long)Kp : 0) + u * 64 + scol;
    const _Float16* src = Bt + (bbase + h * 128 + (tid >> 3)) * (long)lda + ko;
    const _Float16* dst = &Bs[s][h * 8192 + tid * 8];
    __builtin_amdgcn_global_load_lds(
        (const __attribute__((address_space(1))) void*)src,
        (__attribute__((address_space(3))) void*)dst, 16, 0, 0);
    __builtin_amdgcn_global_load_lds(
        (const __attribute__((address_space(1))) void*)(src + 64 * (long)lda),
        (__attribute__((address_space(3))) void*)(dst + 4096), 16, 0, 0);
  };

  // phase: stage -> [vmcnt(4)] -> barrier -> 12 ds_reads -> 32 MFMA
#define PH(slot, ks, WAITV, ...)                                                  \
  do {                                                                            \
    __VA_ARGS__;                                                                  \
    if (WAITV) asm volatile("s_waitcnt vmcnt(4)" ::: "memory");                   \
    __builtin_amdgcn_s_barrier();                                                 \
    const int ch = (((ks) * 4 + (lane >> 4)) ^ (lane & 7)) * 8;                   \
    f16x8 af[8], bfr[4];                                                          \
    _Pragma("unroll")                                                             \
    for (int mi = 0; mi < 8; ++mi)                                                \
      af[mi] = *(const f16x8*)&As[slot][(wm + mi * 16 + lr) * 64 + ch];           \
    _Pragma("unroll")                                                             \
    for (int n = 0; n < 4; ++n)                                                   \
      bfr[n] = *(const f16x8*)&Bs[slot][(wn + n * 16 + lr) * 64 + ch];            \
    __builtin_amdgcn_s_setprio(1);                                                \
    _Pragma("unroll")                                                             \
    for (int mi = 0; mi < 8; ++mi)                                                \
      _Pragma("unroll")                                                           \
      for (int n = 0; n < 4; ++n)                                                 \
        acc[mi][n] = __builtin_amdgcn_mfma_f32_16x16x32_f16(                      \
            af[mi], bfr[n], acc[mi][n], 0, 0, 0);                                 \
    __builtin_amdgcn_s_setprio(0);                                                \
  } while (0)

  // prologue: full tile 0 -> S0 (8 loads/thread outstanding)
  stageA(0, 0, 0); stageA(0, 0, 1); stageB(0, 0, 0); stageB(0, 0, 1);

  for (int i = 0; i < NI; ++i) {
    const int b = 2 * i + 1;
    const int c = (2 * i + 2 < NT) ? 2 * i + 2 : 0;   // tail: harmless re-stage
    PH(0, 0, 1, stageA(b, 1, 0); stageA(b, 1, 1));
    PH(0, 1, 0, stageB(b, 1, 0); stageB(b, 1, 1));
    PH(1, 0, 1, stageA(c, 0, 0); stageA(c, 0, 1));
    PH(1, 1, 0, stageB(c, 0, 0); stageB(c, 0, 1));
  }
  asm volatile("s_waitcnt vmcnt(0)" ::: "memory");

#undef PH

  // epilogue: C/D layout col=lane&15, row=(lane>>4)*4+reg
  const int crow0 = bm * 256 + wm + (lane >> 4) * 4;
  const int ccol0 = bn * 256 + wn + lr;
#pragma unroll
  for (int n = 0; n < 4; n++) {
    const int col = ccol0 + n * 16;
    const float bv = bias[col];
#pragma unroll
    for (int m = 0; m < 8; m++) {
#pragma unroll
      for (int r = 0; r < 4; r++) {
        float v = acc[m][n][r] + bv;
        const long row = crow0 + m * 16 + r;
        if (EPI == 0) {
          v = (v >= 0.f) ? v : 0.01f * v;
          _Float16 hi, lo; split_f16(v, hi, lo);
          _Float16* C = (_Float16*)Cout;
          C[row * (long)(2 * N) + col]     = hi;
          C[row * (long)(2 * N) + N + col] = lo;
        } else {
          ((float*)Cout)[row * (long)N + col] = v;
        }
      }
    }
  }
}

// ---------------- quat -> rotmat, write rot (d_out) + Lf (ws, f32) ----------------
__global__ void quat_rot_kernel(const float* __restrict__ q, const float* __restrict__ offs,
                                float* __restrict__ rot, float* __restrict__ Lf)
{
  const int s = blockIdx.x * 256 + threadIdx.x;
  const int j = blockIdx.y;
  const float* qp = q + (long)s * QSTR + j * 4;
  float qw = qp[0], qx = qp[1], qy = qp[2], qz = qp[3];
  float n = sqrtf(qw * qw + qx * qx + qy * qy + qz * qz);
  n = fmaxf(n, 1e-8f);
  float inv = 1.f / n;
  qw *= inv; qx *= inv; qy *= inv; qz *= inv;
  const float xx = qx * qx, yy = qy * qy, zz = qz * qz;
  const float xy = qx * qy, xz = qx * qz, yz = qy * qz;
  const float xw = qx * qw, yw = qy * qw, zw = qz * qw;
  const float r00 = 1.f - 2.f * (yy + zz), r01 = 2.f * (xy - zw), r02 = 2.f * (xz + yw);
  const float r10 = 2.f * (xy + zw), r11 = 1.f - 2.f * (xx + zz), r12 = 2.f * (yz - xw);
  const float r20 = 2.f * (xz - yw), r21 = 2.f * (yz + xw), r22 = 1.f - 2.f * (xx + yy);

  float4* ro = (float4*)(rot + ((long)s * JN + j) * 16);
  ro[0] = make_float4(r00, r01, r02, 0.f);
  ro[1] = make_float4(r10, r11, r12, 0.f);
  ro[2] = make_float4(r20, r21, r22, 0.f);
  ro[3] = make_float4(0.f, 0.f, 0.f, 1.f);

  const float tx = offs[j * 3 + 0], ty = offs[j * 3 + 1], tz = offs[j * 3 + 2];
  float* L = Lf + (long)j * 12 * B_ + s;
  L[0L * B_]  = r00; L[1L * B_]  = r01; L[2L * B_]  = r02; L[3L * B_]  = tx;
  L[4L * B_]  = r10; L[5L * B_]  = r11; L[6L * B_]  = r12; L[7L * B_]  = ty;
  L[8L * B_]  = r20; L[9L * B_]  = r21; L[10L * B_] = r22; L[11L * B_] = tz;
}

// ---------------- forward kinematics (all fp32) ----------------
struct FkParams { int par[JN]; unsigned long long childmask; };

__global__ void fk_kernel(const float* __restrict__ Lf, float* __restrict__ Gt,
                          float* __restrict__ pose, FkParams P)
{
  const int s = blockIdx.x * 256 + threadIdx.x;
  float G[12];
#pragma unroll
  for (int e = 0; e < 12; e++) G[e] = Lf[(long)e * B_ + s];
  if (P.childmask & 1ull) {
#pragma unroll
    for (int e = 0; e < 12; e++) Gt[(long)e * B_ + s] = G[e];
  }
  pose[(long)s * (JN * 3) + 0] = G[3];
  pose[(long)s * (JN * 3) + 1] = G[7];
  pose[(long)s * (JN * 3) + 2] = G[11];

  for (int j = 1; j < JN; j++) {
    const int p = P.par[j];
    float Pm[12];
    if (p == j - 1) {
#pragma unroll
      for (int e = 0; e < 12; e++) Pm[e] = G[e];
    } else {
#pragma unroll
      for (int e = 0; e < 12; e++) Pm[e] = Gt[((long)p * 12 + e) * B_ + s];
    }
    float L[12];
#pragma unroll
    for (int e = 0; e < 12; e++) L[e] = Lf[((long)j * 12 + e) * B_ + s];
#pragma unroll
    for (int r = 0; r < 3; r++) {
#pragma unroll
      for (int c = 0; c < 4; c++) {
        float v = Pm[r * 4 + 0] * L[0 * 4 + c] + Pm[r * 4 + 1] * L[1 * 4 + c]
                + Pm[r * 4 + 2] * L[2 * 4 + c];
        if (c == 3) v += Pm[r * 4 + 3];
        G[r * 4 + c] = v;
      }
    }
    if ((P.childmask >> j) & 1ull) {
#pragma unroll
      for (int e = 0; e < 12; e++) Gt[((long)j * 12 + e) * B_ + s] = G[e];
    }
    pose[(long)s * (JN * 3) + j * 3 + 0] = G[3];
    pose[(long)s * (JN * 3) + j * 3 + 1] = G[7];
    pose[(long)s * (JN * 3) + j * 3 + 2] = G[11];
  }
}

// ---------------- host: replicate np.random.default_rng(7) parents ----------------
static void compute_parents(int* par, unsigned long long* childmask)
{
  uint32_t pool[4];
  uint32_t hc = 0x43b0d7e5u;                       // INIT_A
  auto hashmix = [&hc](uint32_t v) {
    v ^= hc; hc *= 0x931e8875u; v *= hc; v ^= v >> 16; return v;
  };
  auto mix = [](uint32_t x, uint32_t y) {
    uint32_t r = 0xca01f9ddu * x - 0x4973f715u * y;
    r ^= r >> 16;
    return r;
  };
  const uint32_t entropy[1] = {7u};
  for (int i = 0; i < 4; i++) pool[i] = hashmix(i < 1 ? entropy[i] : 0u);
  for (int si = 0; si < 4; si++)
    for (int di = 0; di < 4; di++)
      if (si != di) pool[di] = mix(pool[di], hashmix(pool[si]));
  uint32_t gs[8];
  uint32_t hb = 0x8b51f9ddu;                       // INIT_B
  for (int i = 0; i < 8; i++) {
    uint32_t dv = pool[i & 3];
    dv ^= hb; hb *= 0x58f38dedu; dv *= hb; dv ^= dv >> 16;
    gs[i] = dv;
  }
  uint64_t sw0 = (uint64_t)gs[0] | ((uint64_t)gs[1] << 32);
  uint64_t sw1 = (uint64_t)gs[2] | ((uint64_t)gs[3] << 32);
  uint64_t iw0 = (uint64_t)gs[4] | ((uint64_t)gs[5] << 32);
  uint64_t iw1 = (uint64_t)gs[6] | ((uint64_t)gs[7] << 32);
  const __uint128_t MULT = (((__uint128_t)0x2360ed051fc65da4ULL) << 64) | 0x4385df649fccf645ULL;
  __uint128_t inc = ((((__uint128_t)iw0 << 64) | iw1) << 1) | 1;
  __uint128_t state = 0;
  state = state * MULT + inc;
  state += (((__uint128_t)sw0) << 64) | sw1;
  state = state * MULT + inc;
  bool has32 = false; uint32_t buf32 = 0;
  auto next64 = [&]() {
    state = state * MULT + inc;
    uint64_t hi = (uint64_t)(state >> 64), lo = (uint64_t)state;
    uint32_t rot = (uint32_t)(state >> 122);
    uint64_t x = hi ^ lo;
    return (x >> rot) | (x << ((64u - rot) & 63u));
  };
  auto next32 = [&]() -> uint32_t {
    if (has32) { has32 = false; return buf32; }
    uint64_t v = next64();
    has32 = true; buf32 = (uint32_t)(v >> 32);
    return (uint32_t)v;
  };
  par[0] = -1;
  for (int j = 1; j < JN; j++) {
    uint32_t rng = (uint32_t)(j - 1);
    if (rng == 0) { par[j] = 0; continue; }
    uint32_t rng_excl = rng + 1;
    uint64_t m = (uint64_t)next32() * (uint64_t)rng_excl;
    uint32_t leftover = (uint32_t)m;
    if (leftover < rng_excl) {
      uint32_t threshold = (uint32_t)((0x100000000ULL - rng_excl) % rng_excl);
      while (leftover < threshold) {
        m = (uint64_t)next32() * (uint64_t)rng_excl;
        leftover = (uint32_t)m;
      }
    }
    par[j] = (int)(m >> 32);
  }
  unsigned long long cm = 0;
  for (int j = 1; j < JN; j++) cm |= 1ull << par[j];
  *childmask = cm;
}

// ---------------- launch ----------------
extern "C" void kernel_launch(void* const* d_in, const int* in_sizes, int n_in,
                              void* d_out, int out_size, void* d_ws, size_t ws_size,
                              hipStream_t stream)
{
  const float* in_seq = (const float*)d_in[0];
  const float* w1 = (const float*)d_in[1];
  const float* b1 = (const float*)d_in[2];
  const float* w2 = (const float*)d_in[3];
  const float* b2 = (const float*)d_in[4];
  const float* w3 = (const float*)d_in[5];
  const float* b3 = (const float*)d_in[6];
  const float* w4 = (const float*)d_in[7];
  const float* b4 = (const float*)d_in[8];
  const float* offs = (const float*)d_in[9];

  char* pR1 = (char*)d_ws;
  char* pR2 = pR1 + 35390464;
  char* pR3 = pR2 + 134217728;
  _Float16* x2  = (_Float16*)pR1;
  _Float16* w1f = (_Float16*)(pR1 + 25165824);
  _Float16* w2f = (_Float16*)(pR1 + 25165824 + 786432);
  _Float16* w3f = (_Float16*)(pR1 + 25165824 + 786432 + 4194304);
  _Float16* w4f = (_Float16*)(pR1 + 25165824 + 786432 + 2 * 4194304);
  float*    b4p = (float*)(pR1 + 25165824 + 786432 + 2 * 4194304 + 1048576);
  float*    q   = (float*)pR1;            // overwrites x2/w1f/w2f/w3f only
  _Float16* h1  = (_Float16*)pR2;
  _Float16* h3  = (_Float16*)pR2;
  float*    Gt  = (float*)pR2;
  _Float16* h2  = (_Float16*)pR3;
  float*    Lf  = (float*)pR3;

  float* pose = (float*)d_out;                        // [B_,57,3]
  float* rot  = (float*)d_out + (long)B_ * JN * 3;    // [B_,57,4,4]

  // prep
  prep_x2_kernel<<<(B_ * 192) / 256, 256, 0, stream>>>(in_seq, x2);
  prep_w2_kernel<<<(1024 * 192) / 256, 256, 0, stream>>>(w1, w1f, 171, 192, 1024);
  prep_w2_kernel<<<(1024 * 1024) / 256, 256, 0, stream>>>(w2, w2f, 1024, 1024, 1024);
  prep_w2_kernel<<<(1024 * 1024) / 256, 256, 0, stream>>>(w3, w3f, 1024, 1024, 1024);
  prep_w2_kernel<<<(256 * 1024) / 256, 256, 0, stream>>>(w4, w4f, 1024, 1024, 228);
  prep_b4_kernel<<<1, 256, 0, stream>>>(b4, b4p);

  // MLP (split-f16, virtual 3K)
  gemm_hl<0><<<(B_ / 128) * (1024 / 128), 256, 0, stream>>>(x2, w1f, b1, h1, B_, 1024, 192);
  gemm256<0><<<(B_ / 256) * (1024 / 256), 512, 0, stream>>>(h1, w2f, b2, h2, B_, 1024, 1024);
  gemm256<0><<<(B_ / 256) * (1024 / 256), 512, 0, stream>>>(h2, w3f, b3, h3, B_, 1024, 1024);
  gemm256<1><<<(B_ / 256) * (QSTR / 256), 512, 0, stream>>>(h3, w4f, b4p, q, B_, QSTR, 1024);

  // epilogue
  quat_rot_kernel<<<dim3(B_ / 256, JN), 256, 0, stream>>>(q, offs, rot, Lf);

  FkParams P;
  compute_parents(P.par, &P.childmask);
  fk_kernel<<<B_ / 256, 256, 0, stream>>>(Lf, Gt, pose, P);
}